// Round 9
// baseline (141.736 us; speedup 1.0000x reference)
//
#include <hip/hip_runtime.h>
#include <hip/hip_bf16.h>

#define B_ 4
#define S_ 4096
#define DM 1024
#define H_ 16
#define HD 64
#define BH (B_*H_)
#define SPLIT 16
#define CHUNK (S_/SPLIT)   // 256
#define SUB 32             // s-rows per staged buffer

typedef __attribute__((ext_vector_type(8))) __bf16 bf16x8;
typedef __attribute__((ext_vector_type(4))) __bf16 bf16x4;
typedef __attribute__((ext_vector_type(4))) float f32x4;

#define MFMA16(a,b,c) __builtin_amdgcn_mfma_f32_16x16x32_bf16((a),(b),(c),0,0,0)

__device__ __forceinline__ void gload_lds16(const void* g, void* l) {
  __builtin_amdgcn_global_load_lds(
      (const __attribute__((address_space(1))) void*)g,
      (__attribute__((address_space(3))) void*)l, 16, 0, 0);
}

// ---------------------------------------------------------------------------
// K1 v5: partial KV[split][bh][d][e] = sum_s K[s][d]*V[s][e], f32 VALU.
// grid = SPLIT*BH = 1024 blocks -> 4 blocks/CU (was 2: latency-bound fix).
// LDS 32 KiB (2-buf x 32 rows x 64 f32 x {K,V}). 8x8 thread tile, wave-
// strided s. Two-stage cross-wave reduction through the dead staging LDS.
// ---------------------------------------------------------------------------
__global__ __launch_bounds__(256)
void k1_kv(const float* __restrict__ Kg, const float* __restrict__ Vg,
           float* __restrict__ partial) {
  // floats: [0,2048)=K0 [2048,4096)=K1 [4096,6144)=V0 [6144,8192)=V1
  __shared__ __align__(16) float sh[8192];
  const int bid = blockIdx.x;
  const int split = bid >> 6, bh = bid & 63;
  const int b = bh >> 4, h = bh & 15;
  const int t = threadIdx.x, w = t >> 6, l = t & 63;
  const int s0 = split * CHUNK;
  const float* Ksrc = Kg + ((size_t)b * S_ + s0) * DM + h * HD;
  const float* Vsrc = Vg + ((size_t)b * S_ + s0) * DM + h * HD;
  const int td = (l >> 3) * 8, te = (l & 7) * 8;
  float acc[8][8] = {};

  auto stage = [&](int bi, int sc) {
    const char* Kp = (const char*)(Ksrc + (size_t)sc * SUB * DM);
    const char* Vp = (const char*)(Vsrc + (size_t)sc * SUB * DM);
    char* Kl = (char*)(sh + bi * 2048);
    char* Vl = (char*)(sh + 4096 + bi * 2048);
#pragma unroll
    for (int it = 0; it < 2; ++it) {
      const int idx = it * 256 + t;
      const int row = idx >> 4, ch = idx & 15;       // 32 rows x 16 granules
      const int ldso = (it * 256 + w * 64) * 16;     // wave-uniform base
      gload_lds16((const void*)(Kp + (size_t)row * 4096 + ch * 16), (void*)(Kl + ldso));
      gload_lds16((const void*)(Vp + (size_t)row * 4096 + ch * 16), (void*)(Vl + ldso));
    }
  };

  stage(0, 0);
  asm volatile("s_waitcnt vmcnt(0)" ::: "memory");
  __builtin_amdgcn_s_barrier();

  for (int hc = 0; hc < CHUNK / SUB; ++hc) {
    const int cur = hc & 1;
    if (hc + 1 < CHUNK / SUB) stage(cur ^ 1, hc + 1);   // prefetch overlaps compute
    const float* Ks = sh + cur * 2048;
    const float* Vs = sh + 4096 + cur * 2048;
#pragma unroll
    for (int si = 0; si < SUB / 4; ++si) {
      const int s = si * 4 + w;                        // wave-strided s
      f32x4 ka = *reinterpret_cast<const f32x4*>(Ks + s * 64 + td);
      f32x4 kb = *reinterpret_cast<const f32x4*>(Ks + s * 64 + td + 4);
      f32x4 va = *reinterpret_cast<const f32x4*>(Vs + s * 64 + te);
      f32x4 vb = *reinterpret_cast<const f32x4*>(Vs + s * 64 + te + 4);
#pragma unroll
      for (int i = 0; i < 4; ++i)
#pragma unroll
        for (int j = 0; j < 4; ++j) {
          acc[i][j]         = fmaf(ka[i], va[j], acc[i][j]);
          acc[i][j + 4]     = fmaf(ka[i], vb[j], acc[i][j + 4]);
          acc[i + 4][j]     = fmaf(kb[i], va[j], acc[i + 4][j]);
          acc[i + 4][j + 4] = fmaf(kb[i], vb[j], acc[i + 4][j + 4]);
        }
    }
    asm volatile("s_waitcnt vmcnt(0)" ::: "memory");
    __builtin_amdgcn_s_barrier();
  }

  // ---- two-stage cross-wave reduction (staging LDS is dead now) ----
  float* red = sh;   // 8192 floats = two 4096-element wave tiles
  if (w >= 2) {
    float* dl = red + (w - 2) * 4096;
#pragma unroll
    for (int i = 0; i < 8; ++i)
#pragma unroll
      for (int jc = 0; jc < 2; ++jc) {
        f32x4 o;
#pragma unroll
        for (int j = 0; j < 4; ++j) o[j] = acc[i][jc * 4 + j];
        *reinterpret_cast<f32x4*>(dl + (td + i) * 64 + te + jc * 4) = o;
      }
  }
  __syncthreads();
  if (w < 2) {
    const float* sl = red + w * 4096;
#pragma unroll
    for (int i = 0; i < 8; ++i)
#pragma unroll
      for (int jc = 0; jc < 2; ++jc) {
        f32x4 v = *reinterpret_cast<const f32x4*>(sl + (td + i) * 64 + te + jc * 4);
#pragma unroll
        for (int j = 0; j < 4; ++j) acc[i][jc * 4 + j] += v[j];
      }
  }
  __syncthreads();
  if (w == 1) {
#pragma unroll
    for (int i = 0; i < 8; ++i)
#pragma unroll
      for (int jc = 0; jc < 2; ++jc) {
        f32x4 o;
#pragma unroll
        for (int j = 0; j < 4; ++j) o[j] = acc[i][jc * 4 + j];
        *reinterpret_cast<f32x4*>(red + (td + i) * 64 + te + jc * 4) = o;
      }
  }
  __syncthreads();
  if (w == 0) {
    float* dst = partial + ((size_t)(split * BH + bh) << 12);
#pragma unroll
    for (int i = 0; i < 8; ++i)
#pragma unroll
      for (int jc = 0; jc < 2; ++jc) {
        f32x4 v = *reinterpret_cast<const f32x4*>(red + (td + i) * 64 + te + jc * 4);
        f32x4 o;
#pragma unroll
        for (int j = 0; j < 4; ++j) o[j] = acc[i][jc * 4 + j] + v[j];
        *reinterpret_cast<f32x4*>(dst + (td + i) * 64 + te + jc * 4) = o;
      }
  }
}

// ---------------------------------------------------------------------------
// K2: reduce 16 partials -> kvt[bh][d][e] bf16.  grid = BH*4 = 256 blocks.
// ---------------------------------------------------------------------------
__global__ __launch_bounds__(256)
void k2_kv_reduce(const float* __restrict__ partial,
                  __bf16* __restrict__ kvt) {
  const int bid = blockIdx.x;
  const int bh = bid >> 2, q = bid & 3;
  const int t = threadIdx.x;
#pragma unroll
  for (int i = 0; i < 4; ++i) {
    const int idx = q * 1024 + i * 256 + t;   // d*64+e
    float s = 0.f;
#pragma unroll
    for (int sp = 0; sp < SPLIT; ++sp)
      s += partial[((size_t)(sp * BH + bh) << 12) + idx];
    kvt[((size_t)bh << 12) + idx] = (__bf16)s;
  }
}

// ---------------------------------------------------------------------------
// K2.5: Ut[b][n][h*64+d] = sum_e W[n][h*64+e] * KV[bh][d][e]   (bf16 out)
// grid = BH*4 = 256 blocks.  (unchanged, verified)
// ---------------------------------------------------------------------------
__global__ __launch_bounds__(256)
void k25_u(const float* __restrict__ Wg,
           const __bf16* __restrict__ kvt,
           __bf16* __restrict__ Ut) {
  const int bid = blockIdx.x;
  const int bh = bid >> 2, nblk = bid & 3;
  const int b = bh >> 4, h = bh & 15;
  const int t = threadIdx.x, w = t >> 6, l = t & 63, lr = l & 15, lg = l >> 4;
  const int n0w = nblk * 256 + w * 64;
  const __bf16* kvb = kvt + ((size_t)bh << 12);
  f32x4 acc[4][4] = {};
#pragma unroll
  for (int ks = 0; ks < 2; ++ks) {
    bf16x8 bfr[4];
#pragma unroll
    for (int nf = 0; nf < 4; ++nf)
      bfr[nf] = *reinterpret_cast<const bf16x8*>(kvb + (nf * 16 + lr) * 64 + ks * 32 + lg * 8);
#pragma unroll
    for (int mf = 0; mf < 4; ++mf) {
      const int n = n0w + mf * 16 + lr;
      const float* wp = Wg + (size_t)n * DM + h * 64 + ks * 32 + lg * 8;
      f32x4 w0 = *reinterpret_cast<const f32x4*>(wp);
      f32x4 w1 = *reinterpret_cast<const f32x4*>(wp + 4);
      bf16x8 af;
#pragma unroll
      for (int j = 0; j < 4; ++j) { af[j] = (__bf16)w0[j]; af[4 + j] = (__bf16)w1[j]; }
#pragma unroll
      for (int nf = 0; nf < 4; ++nf)
        acc[mf][nf] = MFMA16(af, bfr[nf], acc[mf][nf]);
    }
  }
  __bf16* ub = Ut + ((size_t)b << 20);
#pragma unroll
  for (int mf = 0; mf < 4; ++mf)
#pragma unroll
    for (int nf = 0; nf < 4; ++nf)
#pragma unroll
      for (int r = 0; r < 4; ++r) {
        const int n = n0w + mf * 16 + lg * 4 + r;
        ub[(size_t)n * DM + h * 64 + nf * 16 + lr] = (__bf16)acc[mf][nf][r];
      }
}

// ---------------------------------------------------------------------------
// K4 v2: out[b] = Q[b](f32) @ Ut[b]^T + bias.  4 x (M=4096, N=1024, K=1024).
// A = Q staged as RAW F32 via global_load_lds (32 KiB tile), 32B-unit XOR
// swizzle (u ^= row&7 -> <=2-way conflicts, free), f32->bf16 at fragment
// build. B = Ut bf16, proven swizzled path. Kills the k0q cast kernel and
// the 32 MiB Qb intermediate. 2-barrier structure unchanged.
// ---------------------------------------------------------------------------
__global__ __launch_bounds__(256)
void k4_out_gemm(const float* __restrict__ Qg,
                 const __bf16* __restrict__ Ut,
                 const float* __restrict__ biasg,
                 float* __restrict__ outg) {
  __shared__ __align__(16) float Af[128 * 64];     // 32 KiB (f32 A-tile)
  __shared__ __align__(16) __bf16 Bl[128 * 64];    // 16 KiB
  const int bid = blockIdx.x;
  const int b = bid >> 8, rem = bid & 255;
  const int nblk = rem >> 5, mblk = rem & 31;
  const int m0 = mblk * 128, n0 = nblk * 128;
  const int t = threadIdx.x, wid = t >> 6, l = t & 63, lr = l & 15, lg = l >> 4;
  const int wr = wid >> 1, wc = wid & 1;
  const float* Ab = Qg + (size_t)b * S_ * DM;
  const __bf16* Bb = Ut + ((size_t)b << 20);
  f32x4 acc[4][4] = {};

  for (int kt = 0; kt < 16; ++kt) {
    const int k0 = kt * 64;
    // stage A (f32): 128 rows x 16 granules(16B); source col pre-swizzled
#pragma unroll
    for (int it = 0; it < 8; ++it) {
      const int idx = it * 256 + t;
      const int row = idx >> 4, g = idx & 15;
      const int gc = g ^ ((row & 7) << 1);           // 32B-unit XOR swizzle
      gload_lds16((const void*)(Ab + (size_t)(m0 + row) * DM + k0 + gc * 4),
                  (void*)((char*)Af + (it * 256 + wid * 64) * 16));
    }
    // stage B (bf16): 128 rows x 8 granules(16B)
#pragma unroll
    for (int it = 0; it < 4; ++it) {
      const int idx = it * 256 + t;
      const int row = idx >> 3, c = idx & 7;
      const int gc = c ^ (row & 7);
      gload_lds16((const void*)(Bb + (size_t)(n0 + row) * DM + k0 + gc * 8),
                  (void*)((char*)Bl + (it * 256 + wid * 64) * 16));
    }
    __syncthreads();
#pragma unroll
    for (int ks = 0; ks < 2; ++ks) {
      bf16x8 af[4], bfr[4];
#pragma unroll
      for (int mt = 0; mt < 4; ++mt) {
        const int row = wr * 64 + mt * 16 + lr;
        const int up = (ks * 4 + lg) ^ (row & 7);    // 32B unit, swizzled
        const float* p = reinterpret_cast<const float*>((const char*)Af + row * 256 + up * 32);
        f32x4 lo = *reinterpret_cast<const f32x4*>(p);
        f32x4 hi = *reinterpret_cast<const f32x4*>(p + 4);
#pragma unroll
        for (int j = 0; j < 4; ++j) { af[mt][j] = (__bf16)lo[j]; af[mt][4 + j] = (__bf16)hi[j]; }
      }
#pragma unroll
      for (int nt = 0; nt < 4; ++nt) {
        const int row = wc * 64 + nt * 16 + lr;
        const int ch = (ks * 4 + lg) ^ (row & 7);
        bfr[nt] = *reinterpret_cast<const bf16x8*>((const char*)Bl + row * 128 + ch * 16);
      }
#pragma unroll
      for (int mt = 0; mt < 4; ++mt)
#pragma unroll
        for (int nt = 0; nt < 4; ++nt)
          acc[mt][nt] = MFMA16(af[mt], bfr[nt], acc[mt][nt]);
    }
    __syncthreads();
  }

  // epilogue: + f32 bias, f32 store
#pragma unroll
  for (int nt = 0; nt < 4; ++nt) {
    const int colg = n0 + wc * 64 + nt * 16 + lr;
    const float bv = biasg[colg];
#pragma unroll
    for (int mt = 0; mt < 4; ++mt)
#pragma unroll
      for (int r = 0; r < 4; ++r) {
        const int rowg = m0 + wr * 64 + mt * 16 + lg * 4 + r;
        outg[((size_t)b * S_ + rowg) * DM + colg] = acc[mt][nt][r] + bv;
      }
  }
}

extern "C" void kernel_launch(void* const* d_in, const int* in_sizes, int n_in,
                              void* d_out, int out_size, void* d_ws, size_t ws_size,
                              hipStream_t stream) {
  const float* Q = (const float*)d_in[0];
  const float* K = (const float*)d_in[1];
  const float* V = (const float*)d_in[2];
  const float* W = (const float*)d_in[3];
  const float* bias = (const float*)d_in[4];
  float* out = (float*)d_out;

  char* ws = (char*)d_ws;
  float* partial = (float*)ws;                        // 16 MiB @ 0
  __bf16* kvt = (__bf16*)(ws + (16u << 20));          // 512 KiB
  __bf16* Ut  = (__bf16*)(ws + (17u << 20));          // 8 MiB   (total 25 MiB)

  hipLaunchKernelGGL(k1_kv, dim3(SPLIT * BH), dim3(256), 0, stream, K, V, partial);
  hipLaunchKernelGGL(k2_kv_reduce, dim3(BH * 4), dim3(256), 0, stream, partial, kvt);
  hipLaunchKernelGGL(k25_u, dim3(BH * 4), dim3(256), 0, stream, W, kvt, Ut);
  hipLaunchKernelGGL(k4_out_gemm, dim3(1024), dim3(256), 0, stream, Q, Ut, bias, out);
}

// Round 10
// 139.702 us; speedup vs baseline: 1.0146x; 1.0146x over previous
//
#include <hip/hip_runtime.h>
#include <hip/hip_bf16.h>

#define B_ 4
#define S_ 4096
#define DM 1024
#define H_ 16
#define HD 64
#define BH (B_*H_)
#define SPLIT 16
#define CHUNK (S_/SPLIT)   // 256
#define SUB 32             // s-rows per staged buffer

typedef __attribute__((ext_vector_type(8))) __bf16 bf16x8;
typedef __attribute__((ext_vector_type(4))) __bf16 bf16x4;
typedef __attribute__((ext_vector_type(4))) float f32x4;

#define MFMA16(a,b,c) __builtin_amdgcn_mfma_f32_16x16x32_bf16((a),(b),(c),0,0,0)

__device__ __forceinline__ void gload_lds16(const void* g, void* l) {
  __builtin_amdgcn_global_load_lds(
      (const __attribute__((address_space(1))) void*)g,
      (__attribute__((address_space(3))) void*)l, 16, 0, 0);
}

// ---------------------------------------------------------------------------
// K0q: Q f32 -> bf16 streaming cast. (proven)
// ---------------------------------------------------------------------------
__global__ __launch_bounds__(256)
void k0_convq(const float* __restrict__ Qg, __bf16* __restrict__ Qb) {
  const size_t t = (size_t)blockIdx.x * 256 + threadIdx.x;
#pragma unroll
  for (int it = 0; it < 4; ++it) {
    const size_t i = (size_t)it * 1048576 + t;
    f32x4 w = *reinterpret_cast<const f32x4*>(Qg + i * 4);
    bf16x4 o;
#pragma unroll
    for (int j = 0; j < 4; ++j) o[j] = (__bf16)w[j];
    *reinterpret_cast<bf16x4*>(Qb + i * 4) = o;
  }
}

// ---------------------------------------------------------------------------
// K1 v5 (unchanged from round 9 — first clean measurement this round).
// ---------------------------------------------------------------------------
__global__ __launch_bounds__(256)
void k1_kv(const float* __restrict__ Kg, const float* __restrict__ Vg,
           float* __restrict__ partial) {
  __shared__ __align__(16) float sh[8192];
  const int bid = blockIdx.x;
  const int split = bid >> 6, bh = bid & 63;
  const int b = bh >> 4, h = bh & 15;
  const int t = threadIdx.x, w = t >> 6, l = t & 63;
  const int s0 = split * CHUNK;
  const float* Ksrc = Kg + ((size_t)b * S_ + s0) * DM + h * HD;
  const float* Vsrc = Vg + ((size_t)b * S_ + s0) * DM + h * HD;
  const int td = (l >> 3) * 8, te = (l & 7) * 8;
  float acc[8][8] = {};

  auto stage = [&](int bi, int sc) {
    const char* Kp = (const char*)(Ksrc + (size_t)sc * SUB * DM);
    const char* Vp = (const char*)(Vsrc + (size_t)sc * SUB * DM);
    char* Kl = (char*)(sh + bi * 2048);
    char* Vl = (char*)(sh + 4096 + bi * 2048);
#pragma unroll
    for (int it = 0; it < 2; ++it) {
      const int idx = it * 256 + t;
      const int row = idx >> 4, ch = idx & 15;
      const int ldso = (it * 256 + w * 64) * 16;
      gload_lds16((const void*)(Kp + (size_t)row * 4096 + ch * 16), (void*)(Kl + ldso));
      gload_lds16((const void*)(Vp + (size_t)row * 4096 + ch * 16), (void*)(Vl + ldso));
    }
  };

  stage(0, 0);
  asm volatile("s_waitcnt vmcnt(0)" ::: "memory");
  __builtin_amdgcn_s_barrier();

  for (int hc = 0; hc < CHUNK / SUB; ++hc) {
    const int cur = hc & 1;
    if (hc + 1 < CHUNK / SUB) stage(cur ^ 1, hc + 1);
    const float* Ks = sh + cur * 2048;
    const float* Vs = sh + 4096 + cur * 2048;
#pragma unroll
    for (int si = 0; si < SUB / 4; ++si) {
      const int s = si * 4 + w;
      f32x4 ka = *reinterpret_cast<const f32x4*>(Ks + s * 64 + td);
      f32x4 kb = *reinterpret_cast<const f32x4*>(Ks + s * 64 + td + 4);
      f32x4 va = *reinterpret_cast<const f32x4*>(Vs + s * 64 + te);
      f32x4 vb = *reinterpret_cast<const f32x4*>(Vs + s * 64 + te + 4);
#pragma unroll
      for (int i = 0; i < 4; ++i)
#pragma unroll
        for (int j = 0; j < 4; ++j) {
          acc[i][j]         = fmaf(ka[i], va[j], acc[i][j]);
          acc[i][j + 4]     = fmaf(ka[i], vb[j], acc[i][j + 4]);
          acc[i + 4][j]     = fmaf(kb[i], va[j], acc[i + 4][j]);
          acc[i + 4][j + 4] = fmaf(kb[i], vb[j], acc[i + 4][j + 4]);
        }
    }
    asm volatile("s_waitcnt vmcnt(0)" ::: "memory");
    __builtin_amdgcn_s_barrier();
  }

  float* red = sh;
  if (w >= 2) {
    float* dl = red + (w - 2) * 4096;
#pragma unroll
    for (int i = 0; i < 8; ++i)
#pragma unroll
      for (int jc = 0; jc < 2; ++jc) {
        f32x4 o;
#pragma unroll
        for (int j = 0; j < 4; ++j) o[j] = acc[i][jc * 4 + j];
        *reinterpret_cast<f32x4*>(dl + (td + i) * 64 + te + jc * 4) = o;
      }
  }
  __syncthreads();
  if (w < 2) {
    const float* sl = red + w * 4096;
#pragma unroll
    for (int i = 0; i < 8; ++i)
#pragma unroll
      for (int jc = 0; jc < 2; ++jc) {
        f32x4 v = *reinterpret_cast<const f32x4*>(sl + (td + i) * 64 + te + jc * 4);
#pragma unroll
        for (int j = 0; j < 4; ++j) acc[i][jc * 4 + j] += v[j];
      }
  }
  __syncthreads();
  if (w == 1) {
#pragma unroll
    for (int i = 0; i < 8; ++i)
#pragma unroll
      for (int jc = 0; jc < 2; ++jc) {
        f32x4 o;
#pragma unroll
        for (int j = 0; j < 4; ++j) o[j] = acc[i][jc * 4 + j];
        *reinterpret_cast<f32x4*>(red + (td + i) * 64 + te + jc * 4) = o;
      }
  }
  __syncthreads();
  if (w == 0) {
    float* dst = partial + ((size_t)(split * BH + bh) << 12);
#pragma unroll
    for (int i = 0; i < 8; ++i)
#pragma unroll
      for (int jc = 0; jc < 2; ++jc) {
        f32x4 v = *reinterpret_cast<const f32x4*>(red + (td + i) * 64 + te + jc * 4);
        f32x4 o;
#pragma unroll
        for (int j = 0; j < 4; ++j) o[j] = acc[i][jc * 4 + j] + v[j];
        *reinterpret_cast<f32x4*>(dst + (td + i) * 64 + te + jc * 4) = o;
      }
  }
}

// ---------------------------------------------------------------------------
// K2: reduce 16 partials -> kvt[bh][d][e] bf16.  (unchanged)
// ---------------------------------------------------------------------------
__global__ __launch_bounds__(256)
void k2_kv_reduce(const float* __restrict__ partial,
                  __bf16* __restrict__ kvt) {
  const int bid = blockIdx.x;
  const int bh = bid >> 2, q = bid & 3;
  const int t = threadIdx.x;
#pragma unroll
  for (int i = 0; i < 4; ++i) {
    const int idx = q * 1024 + i * 256 + t;
    float s = 0.f;
#pragma unroll
    for (int sp = 0; sp < SPLIT; ++sp)
      s += partial[((size_t)(sp * BH + bh) << 12) + idx];
    kvt[((size_t)bh << 12) + idx] = (__bf16)s;
  }
}

// ---------------------------------------------------------------------------
// K2.5: Ut[b][n][h*64+d] = sum_e W[n][h*64+e]*KV[bh][d][e]  (unchanged)
// ---------------------------------------------------------------------------
__global__ __launch_bounds__(256)
void k25_u(const float* __restrict__ Wg,
           const __bf16* __restrict__ kvt,
           __bf16* __restrict__ Ut) {
  const int bid = blockIdx.x;
  const int bh = bid >> 2, nblk = bid & 3;
  const int b = bh >> 4, h = bh & 15;
  const int t = threadIdx.x, w = t >> 6, l = t & 63, lr = l & 15, lg = l >> 4;
  const int n0w = nblk * 256 + w * 64;
  const __bf16* kvb = kvt + ((size_t)bh << 12);
  f32x4 acc[4][4] = {};
#pragma unroll
  for (int ks = 0; ks < 2; ++ks) {
    bf16x8 bfr[4];
#pragma unroll
    for (int nf = 0; nf < 4; ++nf)
      bfr[nf] = *reinterpret_cast<const bf16x8*>(kvb + (nf * 16 + lr) * 64 + ks * 32 + lg * 8);
#pragma unroll
    for (int mf = 0; mf < 4; ++mf) {
      const int n = n0w + mf * 16 + lr;
      const float* wp = Wg + (size_t)n * DM + h * 64 + ks * 32 + lg * 8;
      f32x4 w0 = *reinterpret_cast<const f32x4*>(wp);
      f32x4 w1 = *reinterpret_cast<const f32x4*>(wp + 4);
      bf16x8 af;
#pragma unroll
      for (int j = 0; j < 4; ++j) { af[j] = (__bf16)w0[j]; af[4 + j] = (__bf16)w1[j]; }
#pragma unroll
      for (int nf = 0; nf < 4; ++nf)
        acc[mf][nf] = MFMA16(af, bfr[nf], acc[mf][nf]);
    }
  }
  __bf16* ub = Ut + ((size_t)b << 20);
#pragma unroll
  for (int mf = 0; mf < 4; ++mf)
#pragma unroll
    for (int nf = 0; nf < 4; ++nf)
#pragma unroll
      for (int r = 0; r < 4; ++r) {
        const int n = n0w + mf * 16 + lg * 4 + r;
        ub[(size_t)n * DM + h * 64 + nf * 16 + lr] = (__bf16)acc[mf][nf][r];
      }
}

// ---------------------------------------------------------------------------
// K4 v3: 256x256 tile, 8 waves (2x4), 512 thr, BK=64, double-buffered 128 KB
// LDS, phase-split K-step with raw barriers + issue-early full-tile prefetch.
// Per wave: 128x64 output = acc[8][4]. B-frags cached across mh-phases.
// Proven XOR granule swizzle (stage source + read). grid = 4*16*4 = 256.
// ---------------------------------------------------------------------------
// PHASE_A: loads bg (B frags for KS) + af(mh=0); PHASE_B: af(mh=1), reuses bg.
#define K4_LOAD_A(AF, MH, KS, ACP)                                             \
  _Pragma("unroll")                                                            \
  for (int i_ = 0; i_ < 4; ++i_) {                                             \
    const int row_ = wr * 128 + ((MH) * 4 + i_) * 16 + lr;                     \
    const int ch_ = ((KS) * 4 + lg) ^ (row_ & 7);                              \
    AF[i_] = *reinterpret_cast<const bf16x8*>((ACP) + row_ * 64 + ch_ * 8);    \
  }

#define K4_LOAD_B(BG, KS, BCP)                                                 \
  _Pragma("unroll")                                                            \
  for (int n_ = 0; n_ < 4; ++n_) {                                             \
    const int row_ = wc * 64 + n_ * 16 + lr;                                   \
    const int ch_ = ((KS) * 4 + lg) ^ (row_ & 7);                              \
    BG[n_] = *reinterpret_cast<const bf16x8*>((BCP) + row_ * 64 + ch_ * 8);    \
  }

#define K4_MFMA(AF, BG, MH)                                                    \
  __builtin_amdgcn_s_setprio(1);                                               \
  _Pragma("unroll")                                                            \
  for (int i_ = 0; i_ < 4; ++i_)                                               \
    _Pragma("unroll")                                                          \
    for (int n_ = 0; n_ < 4; ++n_)                                             \
      acc[(MH) * 4 + i_][n_] = MFMA16(AF[i_], BG[n_], acc[(MH) * 4 + i_][n_]); \
  __builtin_amdgcn_s_setprio(0);

__global__ __launch_bounds__(512, 2)
void k4_gemm256(const __bf16* __restrict__ Qb,
                const __bf16* __restrict__ Ut,
                const float* __restrict__ biasg,
                float* __restrict__ outg) {
  __shared__ __align__(16) __bf16 Al0[256 * 64];
  __shared__ __align__(16) __bf16 Al1[256 * 64];
  __shared__ __align__(16) __bf16 Bl0[256 * 64];
  __shared__ __align__(16) __bf16 Bl1[256 * 64];
  const int bid = blockIdx.x;
  const int b = bid >> 6, rem = bid & 63;
  const int mblk = rem & 15, nblk = rem >> 4;   // 16 m x 4 n
  const int m0 = mblk * 256, n0 = nblk * 256;
  const int t = threadIdx.x;
  const int wid = t >> 6, l = t & 63, lr = l & 15, lg = l >> 4;
  const int wr = wid >> 2, wc = wid & 3;        // 2 x 4 waves
  const __bf16* Ab = Qb + (size_t)b * S_ * DM;
  const __bf16* Bb = Ut + ((size_t)b << 20);
  f32x4 acc[8][4] = {};

  auto stage_tile = [&](__bf16* Ad, __bf16* Bd, int kt) {
    const int k0 = kt * 64;
#pragma unroll
    for (int ci = 0; ci < 4; ++ci) {
      const int idx = ci * 512 + t;             // granule 0..2047
      const int row = idx >> 3, c = idx & 7;
      const int gc = c ^ (row & 7);             // pre-swizzled global source
      const int ldso = (ci * 512 + wid * 64) * 16;   // wave-uniform base
      gload_lds16((const void*)(Ab + (size_t)(m0 + row) * DM + k0 + gc * 8),
                  (void*)((char*)Ad + ldso));
      gload_lds16((const void*)(Bb + (size_t)(n0 + row) * DM + k0 + gc * 8),
                  (void*)((char*)Bd + ldso));
    }
  };

  stage_tile(Al0, Bl0, 0);
  for (int kt = 0; kt < 16; ++kt) {
    const int cur = kt & 1;
    asm volatile("s_waitcnt vmcnt(0)" ::: "memory");   // tile kt landed (issued ~4 phases ago)
    __builtin_amdgcn_s_barrier();                      // all waves done with buf^1 reads
    if (kt < 15) {                                     // issue-early: whole next tile
      if (cur) stage_tile(Al0, Bl0, kt + 1);
      else     stage_tile(Al1, Bl1, kt + 1);
    }
    const __bf16* Ac = cur ? Al1 : Al0;
    const __bf16* Bc = cur ? Bl1 : Bl0;
    bf16x8 af[4], bg[4];
    // ks = 0
    K4_LOAD_B(bg, 0, Bc);
    K4_LOAD_A(af, 0, 0, Ac);
    K4_MFMA(af, bg, 0);
    __builtin_amdgcn_s_barrier();
    K4_LOAD_A(af, 1, 0, Ac);
    K4_MFMA(af, bg, 1);
    __builtin_amdgcn_s_barrier();
    // ks = 1
    K4_LOAD_B(bg, 1, Bc);
    K4_LOAD_A(af, 0, 1, Ac);
    K4_MFMA(af, bg, 0);
    __builtin_amdgcn_s_barrier();
    K4_LOAD_A(af, 1, 1, Ac);
    K4_MFMA(af, bg, 1);
  }

  // epilogue: + f32 bias, f32 store
#pragma unroll
  for (int nf = 0; nf < 4; ++nf) {
    const int colg = n0 + wc * 64 + nf * 16 + lr;
    const float bv = biasg[colg];
#pragma unroll
    for (int mf = 0; mf < 8; ++mf)
#pragma unroll
      for (int r = 0; r < 4; ++r) {
        const int rowg = m0 + wr * 128 + mf * 16 + lg * 4 + r;
        outg[((size_t)b * S_ + rowg) * DM + colg] = acc[mf][nf][r] + bv;
      }
  }
}

extern "C" void kernel_launch(void* const* d_in, const int* in_sizes, int n_in,
                              void* d_out, int out_size, void* d_ws, size_t ws_size,
                              hipStream_t stream) {
  const float* Q = (const float*)d_in[0];
  const float* K = (const float*)d_in[1];
  const float* V = (const float*)d_in[2];
  const float* W = (const float*)d_in[3];
  const float* bias = (const float*)d_in[4];
  float* out = (float*)d_out;

  char* ws = (char*)d_ws;
  float* partial = (float*)ws;                        // 16 MiB @ 0
  __bf16* kvt = (__bf16*)(ws + (16u << 20));          // 512 KiB
  __bf16* Ut  = (__bf16*)(ws + (17u << 20));          // 8 MiB
  __bf16* Qb  = (__bf16*)(ws + (25u << 20));          // 32 MiB

  hipLaunchKernelGGL(k1_kv, dim3(SPLIT * BH), dim3(256), 0, stream, K, V, partial);
  hipLaunchKernelGGL(k0_convq, dim3(4096), dim3(256), 0, stream, Q, Qb);
  hipLaunchKernelGGL(k2_kv_reduce, dim3(BH * 4), dim3(256), 0, stream, partial, kvt);
  hipLaunchKernelGGL(k25_u, dim3(BH * 4), dim3(256), 0, stream, W, kvt, Ut);
  hipLaunchKernelGGL(k4_gemm256, dim3(256), dim3(512), 0, stream, Qb, Ut, bias, out);
}

// Round 11
// 124.074 us; speedup vs baseline: 1.1423x; 1.1260x over previous
//
#include <hip/hip_runtime.h>
#include <hip/hip_bf16.h>

#define B_ 4
#define S_ 4096
#define DM 1024
#define H_ 16
#define HD 64
#define BH (B_*H_)
#define SPLIT 16
#define CHUNK (S_/SPLIT)   // 256
#define SUB 64             // s-rows per staged buffer

typedef __attribute__((ext_vector_type(8))) __bf16 bf16x8;
typedef __attribute__((ext_vector_type(4))) __bf16 bf16x4;
typedef __attribute__((ext_vector_type(4))) float f32x4;

#define MFMA16(a,b,c) __builtin_amdgcn_mfma_f32_16x16x32_bf16((a),(b),(c),0,0,0)

__device__ __forceinline__ void gload_lds16(const void* g, void* l) {
  __builtin_amdgcn_global_load_lds(
      (const __attribute__((address_space(1))) void*)g,
      (__attribute__((address_space(3))) void*)l, 16, 0, 0);
}

// ---------------------------------------------------------------------------
// K0q: Q f32 -> bf16 streaming cast. (proven)
// ---------------------------------------------------------------------------
__global__ __launch_bounds__(256)
void k0_convq(const float* __restrict__ Qg, __bf16* __restrict__ Qb) {
  const size_t t = (size_t)blockIdx.x * 256 + threadIdx.x;
#pragma unroll
  for (int it = 0; it < 4; ++it) {
    const size_t i = (size_t)it * 1048576 + t;
    f32x4 w = *reinterpret_cast<const f32x4*>(Qg + i * 4);
    bf16x4 o;
#pragma unroll
    for (int j = 0; j < 4; ++j) o[j] = (__bf16)w[j];
    *reinterpret_cast<bf16x4*>(Qb + i * 4) = o;
  }
}

// ---------------------------------------------------------------------------
// K1 v6: MFMA KV. partial[split][bh][d][e] = sum_s K[s][d]*V[s][e].
// grid = SPLIT*BH = 1024 blocks (4/CU), 256 thr. The VALU design was LDS-
// port-bound (~16.8 MB LDS reads/CU); MFMA cuts LDS traffic ~26x (matrix
// unit broadcasts operands). Staging: global f32x4 (256B segments) ->
// in-thread 4x4 transpose+cvt -> bf16x4 writes into [d][s] LDS, ST=72
// (144B rows: 16B-aligned frag reads, bank-staggered). Double-buffered,
// loads for chunk hc+1 issued before compute of hc (T14).
// Frag/MFMA/C-write structure identical to the round-2-verified kernel.
// ---------------------------------------------------------------------------
__global__ __launch_bounds__(256)
void k1_kv(const float* __restrict__ Kg, const float* __restrict__ Vg,
           float* __restrict__ partial) {
  constexpr int ST = 72;   // elems per d-row: 64 + 8 pad
  __shared__ __align__(16) __bf16 KT[2][64 * ST];   // 2 x 9 KiB
  __shared__ __align__(16) __bf16 VT[2][64 * ST];   // 2 x 9 KiB  (36 KiB total)
  const int bid = blockIdx.x;
  const int split = bid >> 6, bh = bid & 63;
  const int b = bh >> 4, h = bh & 15;
  const int t = threadIdx.x, w = t >> 6, l = t & 63, lr = l & 15, lg = l >> 4;
  const int s0 = split * CHUNK;
  const float* Ksrc = Kg + ((size_t)b * S_ + s0) * DM + h * HD;
  const float* Vsrc = Vg + ((size_t)b * S_ + s0) * DM + h * HD;
  const int ts = (t >> 4) * 4;   // thread's s-block (coalesced global reads)
  const int td = (t & 15) * 4;   // thread's d-block

  f32x4 kreg[4], vreg[4];

  auto issue = [&](int hc) {
    const float* Kp = Ksrc + (size_t)hc * SUB * DM;
    const float* Vp = Vsrc + (size_t)hc * SUB * DM;
#pragma unroll
    for (int r = 0; r < 4; ++r) {
      kreg[r] = *reinterpret_cast<const f32x4*>(Kp + (size_t)(ts + r) * DM + td);
      vreg[r] = *reinterpret_cast<const f32x4*>(Vp + (size_t)(ts + r) * DM + td);
    }
  };
  auto commit = [&](int bi) {
#pragma unroll
    for (int c = 0; c < 4; ++c) {          // in-thread 4x4 transpose + cvt
      bf16x4 kc, vc;
#pragma unroll
      for (int r = 0; r < 4; ++r) { kc[r] = (__bf16)kreg[r][c]; vc[r] = (__bf16)vreg[r][c]; }
      *reinterpret_cast<bf16x4*>(&KT[bi][(td + c) * ST + ts]) = kc;
      *reinterpret_cast<bf16x4*>(&VT[bi][(td + c) * ST + ts]) = vc;
    }
  };

  f32x4 acc[4] = {};
  issue(0);
  commit(0);
  __syncthreads();

  constexpr int NHC = CHUNK / SUB;   // 4
  for (int hc = 0; hc < NHC; ++hc) {
    const int cur = hc & 1;
    if (hc + 1 < NHC) issue(hc + 1);           // loads fly during compute
#pragma unroll
    for (int ks = 0; ks < 2; ++ks) {
      bf16x8 a = *reinterpret_cast<const bf16x8*>(&KT[cur][(w * 16 + lr) * ST + ks * 32 + lg * 8]);
#pragma unroll
      for (int n = 0; n < 4; ++n) {
        bf16x8 bb = *reinterpret_cast<const bf16x8*>(&VT[cur][(n * 16 + lr) * ST + ks * 32 + lg * 8]);
        acc[n] = MFMA16(a, bb, acc[n]);
      }
    }
    if (hc + 1 < NHC) commit(cur ^ 1);         // cvt+write after compute
    __syncthreads();
  }

  // C-write (verified in round 2): d = w*16 + lg*4 + r, e = n*16 + lr
  float* dst = partial + ((size_t)(split * BH + bh) << 12);
#pragma unroll
  for (int n = 0; n < 4; ++n)
#pragma unroll
    for (int r = 0; r < 4; ++r) {
      const int d = w * 16 + lg * 4 + r;
      const int e = n * 16 + lr;
      dst[d * 64 + e] = acc[n][r];
    }
}

// ---------------------------------------------------------------------------
// K2: reduce 16 partials -> kvt[bh][d][e] bf16.  (unchanged)
// ---------------------------------------------------------------------------
__global__ __launch_bounds__(256)
void k2_kv_reduce(const float* __restrict__ partial,
                  __bf16* __restrict__ kvt) {
  const int bid = blockIdx.x;
  const int bh = bid >> 2, q = bid & 3;
  const int t = threadIdx.x;
#pragma unroll
  for (int i = 0; i < 4; ++i) {
    const int idx = q * 1024 + i * 256 + t;
    float s = 0.f;
#pragma unroll
    for (int sp = 0; sp < SPLIT; ++sp)
      s += partial[((size_t)(sp * BH + bh) << 12) + idx];
    kvt[((size_t)bh << 12) + idx] = (__bf16)s;
  }
}

// ---------------------------------------------------------------------------
// K2.5: Ut[b][n][h*64+d] = sum_e W[n][h*64+e]*KV[bh][d][e]  (unchanged)
// ---------------------------------------------------------------------------
__global__ __launch_bounds__(256)
void k25_u(const float* __restrict__ Wg,
           const __bf16* __restrict__ kvt,
           __bf16* __restrict__ Ut) {
  const int bid = blockIdx.x;
  const int bh = bid >> 2, nblk = bid & 3;
  const int b = bh >> 4, h = bh & 15;
  const int t = threadIdx.x, w = t >> 6, l = t & 63, lr = l & 15, lg = l >> 4;
  const int n0w = nblk * 256 + w * 64;
  const __bf16* kvb = kvt + ((size_t)bh << 12);
  f32x4 acc[4][4] = {};
#pragma unroll
  for (int ks = 0; ks < 2; ++ks) {
    bf16x8 bfr[4];
#pragma unroll
    for (int nf = 0; nf < 4; ++nf)
      bfr[nf] = *reinterpret_cast<const bf16x8*>(kvb + (nf * 16 + lr) * 64 + ks * 32 + lg * 8);
#pragma unroll
    for (int mf = 0; mf < 4; ++mf) {
      const int n = n0w + mf * 16 + lr;
      const float* wp = Wg + (size_t)n * DM + h * 64 + ks * 32 + lg * 8;
      f32x4 w0 = *reinterpret_cast<const f32x4*>(wp);
      f32x4 w1 = *reinterpret_cast<const f32x4*>(wp + 4);
      bf16x8 af;
#pragma unroll
      for (int j = 0; j < 4; ++j) { af[j] = (__bf16)w0[j]; af[4 + j] = (__bf16)w1[j]; }
#pragma unroll
      for (int nf = 0; nf < 4; ++nf)
        acc[mf][nf] = MFMA16(af, bfr[nf], acc[mf][nf]);
    }
  }
  __bf16* ub = Ut + ((size_t)b << 20);
#pragma unroll
  for (int mf = 0; mf < 4; ++mf)
#pragma unroll
    for (int nf = 0; nf < 4; ++nf)
#pragma unroll
      for (int r = 0; r < 4; ++r) {
        const int n = n0w + mf * 16 + lg * 4 + r;
        ub[(size_t)n * DM + h * 64 + nf * 16 + lr] = (__bf16)acc[mf][nf][r];
      }
}

// ---------------------------------------------------------------------------
// K4 v3: 256x256 tile, 8 waves, 512 thr, BK=64, double-buffered 128 KB LDS,
// phase-split K-step, issue-early full-tile prefetch. (unchanged)
// ---------------------------------------------------------------------------
#define K4_LOAD_A(AF, MH, KS, ACP)                                             \
  _Pragma("unroll")                                                            \
  for (int i_ = 0; i_ < 4; ++i_) {                                             \
    const int row_ = wr * 128 + ((MH) * 4 + i_) * 16 + lr;                     \
    const int ch_ = ((KS) * 4 + lg) ^ (row_ & 7);                              \
    AF[i_] = *reinterpret_cast<const bf16x8*>((ACP) + row_ * 64 + ch_ * 8);    \
  }

#define K4_LOAD_B(BG, KS, BCP)                                                 \
  _Pragma("unroll")                                                            \
  for (int n_ = 0; n_ < 4; ++n_) {                                             \
    const int row_ = wc * 64 + n_ * 16 + lr;                                   \
    const int ch_ = ((KS) * 4 + lg) ^ (row_ & 7);                              \
    BG[n_] = *reinterpret_cast<const bf16x8*>((BCP) + row_ * 64 + ch_ * 8);    \
  }

#define K4_MFMA(AF, BG, MH)                                                    \
  __builtin_amdgcn_s_setprio(1);                                               \
  _Pragma("unroll")                                                            \
  for (int i_ = 0; i_ < 4; ++i_)                                               \
    _Pragma("unroll")                                                          \
    for (int n_ = 0; n_ < 4; ++n_)                                             \
      acc[(MH) * 4 + i_][n_] = MFMA16(AF[i_], BG[n_], acc[(MH) * 4 + i_][n_]); \
  __builtin_amdgcn_s_setprio(0);

__global__ __launch_bounds__(512, 2)
void k4_gemm256(const __bf16* __restrict__ Qb,
                const __bf16* __restrict__ Ut,
                const float* __restrict__ biasg,
                float* __restrict__ outg) {
  __shared__ __align__(16) __bf16 Al0[256 * 64];
  __shared__ __align__(16) __bf16 Al1[256 * 64];
  __shared__ __align__(16) __bf16 Bl0[256 * 64];
  __shared__ __align__(16) __bf16 Bl1[256 * 64];
  const int bid = blockIdx.x;
  const int b = bid >> 6, rem = bid & 63;
  const int mblk = rem & 15, nblk = rem >> 4;
  const int m0 = mblk * 256, n0 = nblk * 256;
  const int t = threadIdx.x;
  const int wid = t >> 6, l = t & 63, lr = l & 15, lg = l >> 4;
  const int wr = wid >> 2, wc = wid & 3;
  const __bf16* Ab = Qb + (size_t)b * S_ * DM;
  const __bf16* Bb = Ut + ((size_t)b << 20);
  f32x4 acc[8][4] = {};

  auto stage_tile = [&](__bf16* Ad, __bf16* Bd, int kt) {
    const int k0 = kt * 64;
#pragma unroll
    for (int ci = 0; ci < 4; ++ci) {
      const int idx = ci * 512 + t;
      const int row = idx >> 3, c = idx & 7;
      const int gc = c ^ (row & 7);
      const int ldso = (ci * 512 + wid * 64) * 16;
      gload_lds16((const void*)(Ab + (size_t)(m0 + row) * DM + k0 + gc * 8),
                  (void*)((char*)Ad + ldso));
      gload_lds16((const void*)(Bb + (size_t)(n0 + row) * DM + k0 + gc * 8),
                  (void*)((char*)Bd + ldso));
    }
  };

  stage_tile(Al0, Bl0, 0);
  for (int kt = 0; kt < 16; ++kt) {
    const int cur = kt & 1;
    asm volatile("s_waitcnt vmcnt(0)" ::: "memory");
    __builtin_amdgcn_s_barrier();
    if (kt < 15) {
      if (cur) stage_tile(Al0, Bl0, kt + 1);
      else     stage_tile(Al1, Bl1, kt + 1);
    }
    const __bf16* Ac = cur ? Al1 : Al0;
    const __bf16* Bc = cur ? Bl1 : Bl0;
    bf16x8 af[4], bg[4];
    K4_LOAD_B(bg, 0, Bc);
    K4_LOAD_A(af, 0, 0, Ac);
    K4_MFMA(af, bg, 0);
    __builtin_amdgcn_s_barrier();
    K4_LOAD_A(af, 1, 0, Ac);
    K4_MFMA(af, bg, 1);
    __builtin_amdgcn_s_barrier();
    K4_LOAD_B(bg, 1, Bc);
    K4_LOAD_A(af, 0, 1, Ac);
    K4_MFMA(af, bg, 0);
    __builtin_amdgcn_s_barrier();
    K4_LOAD_A(af, 1, 1, Ac);
    K4_MFMA(af, bg, 1);
  }

#pragma unroll
  for (int nf = 0; nf < 4; ++nf) {
    const int colg = n0 + wc * 64 + nf * 16 + lr;
    const float bv = biasg[colg];
#pragma unroll
    for (int mf = 0; mf < 8; ++mf)
#pragma unroll
      for (int r = 0; r < 4; ++r) {
        const int rowg = m0 + wr * 128 + mf * 16 + lg * 4 + r;
        outg[((size_t)b * S_ + rowg) * DM + colg] = acc[mf][nf][r] + bv;
      }
  }
}

extern "C" void kernel_launch(void* const* d_in, const int* in_sizes, int n_in,
                              void* d_out, int out_size, void* d_ws, size_t ws_size,
                              hipStream_t stream) {
  const float* Q = (const float*)d_in[0];
  const float* K = (const float*)d_in[1];
  const float* V = (const float*)d_in[2];
  const float* W = (const float*)d_in[3];
  const float* bias = (const float*)d_in[4];
  float* out = (float*)d_out;

  char* ws = (char*)d_ws;
  float* partial = (float*)ws;                        // 16 MiB @ 0
  __bf16* kvt = (__bf16*)(ws + (16u << 20));          // 512 KiB
  __bf16* Ut  = (__bf16*)(ws + (17u << 20));          // 8 MiB
  __bf16* Qb  = (__bf16*)(ws + (25u << 20));          // 32 MiB

  hipLaunchKernelGGL(k1_kv, dim3(SPLIT * BH), dim3(256), 0, stream, K, V, partial);
  hipLaunchKernelGGL(k0_convq, dim3(4096), dim3(256), 0, stream, Q, Qb);
  hipLaunchKernelGGL(k2_kv_reduce, dim3(BH * 4), dim3(256), 0, stream, partial, kvt);
  hipLaunchKernelGGL(k25_u, dim3(BH * 4), dim3(256), 0, stream, W, kvt, Ut);
  hipLaunchKernelGGL(k4_gemm256, dim3(256), dim3(512), 0, stream, Qb, Ut, bias, out);
}